// Round 4
// baseline (170.483 us; speedup 1.0000x reference)
//
#include <hip/hip_runtime.h>
#include <math.h>

#define S_LEN  2048
#define BATCH  2
#define DM     1024
#define NHEAD  16
#define DHEAD  64
#define WIN    256
#define MROWS  4096

#define PPAD 68     // f32 LDS row stride for attn P

// gemm_qkv tile geometry (R13): 256x192, BK=64, 8 waves as 4M x 2N
#define BM 256
#define BN 192
#define BK 64

// gemm_out tile geometry (R14): 128x64, BK=64, 4 waves as 2x2 (64x32 wave)
#define OM 128
#define ON 64

typedef __attribute__((ext_vector_type(8))) short bf16x8;
typedef __attribute__((ext_vector_type(4))) float f32x4;

__device__ __forceinline__ unsigned short f2b(float f) {   // RNE
    unsigned int u = __float_as_uint(f);
    return (unsigned short)((u + 0x7fffu + ((u >> 16) & 1u)) >> 16);
}
__device__ __forceinline__ void gld16(const void* g, void* l) {
    __builtin_amdgcn_global_load_lds(
        (const __attribute__((address_space(1))) void*)g,
        (__attribute__((address_space(3))) void*)l, 16, 0, 0);
}
__device__ __forceinline__ bf16x8 pack8(float4 a, float4 b) {
    bf16x8 r;
    r[0] = (short)f2b(a.x); r[1] = (short)f2b(a.y);
    r[2] = (short)f2b(a.z); r[3] = (short)f2b(a.w);
    r[4] = (short)f2b(b.x); r[5] = (short)f2b(b.y);
    r[6] = (short)f2b(b.z); r[7] = (short)f2b(b.w);
    return r;
}

// ---------------------------------------------------------------------------
// fp32 -> bf16 convert (x): 4M elems, 4/thread
// ---------------------------------------------------------------------------
__global__ __launch_bounds__(256)
void cvtx(const float* __restrict__ x, unsigned short* __restrict__ xb)
{
    const int i = (blockIdx.x * 256 + threadIdx.x) * 4;
    float4 f = *(const float4*)(x + i);
    ushort4 o; o.x = f2b(f.x); o.y = f2b(f.y); o.z = f2b(f.z); o.w = f2b(f.w);
    *(ushort4*)(xb + i) = o;
}

// ---------------------------------------------------------------------------
// 4x fused: W (K x N fp32) -> W^T (N x K bf16)
// ---------------------------------------------------------------------------
__global__ __launch_bounds__(256)
void twcvt4(const float* __restrict__ W0, const float* __restrict__ W1,
            const float* __restrict__ W2, const float* __restrict__ W3,
            unsigned short* __restrict__ T0, unsigned short* __restrict__ T1,
            unsigned short* __restrict__ T2, unsigned short* __restrict__ T3)
{
    const int zz = blockIdx.z;
    const float* W = (zz == 0) ? W0 : (zz == 1) ? W1 : (zz == 2) ? W2 : W3;
    unsigned short* WT = (zz == 0) ? T0 : (zz == 1) ? T1 : (zz == 2) ? T2 : T3;

    __shared__ float t32[32][33];
    const int bx = blockIdx.x * 32;
    const int by = blockIdx.y * 32;
    const int c  = threadIdx.x & 31;
    const int r0 = threadIdx.x >> 5;
#pragma unroll
    for (int p = 0; p < 4; ++p)
        t32[r0 + 8 * p][c] = W[(size_t)(by + r0 + 8 * p) * DM + bx + c];
    __syncthreads();
#pragma unroll
    for (int p = 0; p < 4; ++p)
        WT[(size_t)(bx + r0 + 8 * p) * DM + by + c] = f2b(t32[c][r0 + 8 * p]);
}

// ---------------------------------------------------------------------------
// R13 gemm_qkv (unchanged): 256x192, BK=64, 8 waves as 4M x 2N.
// One barrier per K-tile, counted vmcnt, dbuf LDS, XOR chunk swizzle.
// ---------------------------------------------------------------------------
__global__ __launch_bounds__(512, 2)
void gemm_qkv(const unsigned short* __restrict__ A,
              const unsigned short* __restrict__ BT,
              const float* __restrict__ b0,
              const float* __restrict__ b1,
              const float* __restrict__ b2,
              const float* __restrict__ beta,
              unsigned short* __restrict__ Cb)
{
    __shared__ unsigned short Ab[2][BM * BK];   // 2 x 32 KB
    __shared__ unsigned short Bb[2][BN * BK];   // 2 x 24 KB

    const int t   = threadIdx.x;
    const int ln  = t & 63;
    const int wv  = t >> 6;          // 0..7
    const int wr  = wv & 3;          // 4M -> 64-row slice
    const int wc  = wv >> 2;         // 2N -> 96-col slice
    const int m16 = ln & 15;
    const int g   = ln >> 4;         // 0..3
    const int sw  = m16 & 7;         // read-side swizzle key (row & 7)

    const int rowBase = blockIdx.y * BM;
    const int colBase = blockIdx.x * BN;

    const int sr  = t >> 3;                   // 0..63
    const int scx = (t & 7) ^ (sr & 7);       // global col-chunk to fetch
    const size_t gOff = (size_t)sr * DM + scx * 8;
    const int    ldOff = t * 8;               // shorts (t*16 bytes)

    f32x4 acc[4][6];
#pragma unroll
    for (int u = 0; u < 4; ++u)
#pragma unroll
        for (int v = 0; v < 6; ++v)
            acc[u][v] = (f32x4){0.f, 0.f, 0.f, 0.f};

    // prologue: stage K-tile 0 into buffer 0, full drain once
    {
        const unsigned short* a0 = A  + (size_t)rowBase * DM + gOff;
        const unsigned short* bt = BT + (size_t)colBase * DM + gOff;
#pragma unroll
        for (int cb = 0; cb < 3; ++cb)
            gld16(bt + (size_t)cb * 64 * DM, &Bb[0][cb * 4096 + ldOff]);
#pragma unroll
        for (int ca = 0; ca < 4; ++ca)
            gld16(a0 + (size_t)ca * 64 * DM, &Ab[0][ca * 4096 + ldOff]);
        asm volatile("s_waitcnt vmcnt(0)" ::: "memory");
        __builtin_amdgcn_s_barrier();
        __builtin_amdgcn_sched_barrier(0);
    }

    for (int kt = 0; kt < DM / BK; ++kt) {
        const int cur = kt & 1;
        const unsigned short* Ac = Ab[cur];
        const unsigned short* Bc = Bb[cur];
        unsigned short* An = Ab[cur ^ 1];
        unsigned short* Bn = Bb[cur ^ 1];
        const bool hn = (kt < DM / BK - 1);
        const unsigned short* aS = A  + (size_t)rowBase * DM + (kt + 1) * BK + gOff;
        const unsigned short* bS = BT + (size_t)colBase * DM + (kt + 1) * BK + gOff;

        // ---- kk = 0 fragment reads (10 x ds_read_b128) ----
        bf16x8 af0[4], bf0[6];
#pragma unroll
        for (int u = 0; u < 4; ++u)
            af0[u] = *(const bf16x8*)&Ac[(wr * 64 + u * 16 + m16) * BK + ((g ^ sw) * 8)];
#pragma unroll
        for (int v = 0; v < 6; ++v)
            bf0[v] = *(const bf16x8*)&Bc[(wc * 96 + v * 16 + m16) * BK + ((g ^ sw) * 8)];

        // ---- stage ALL of tile kt+1 now (7 loads, waited at end of iter) ----
        if (hn) {
            gld16(bS,                    &Bn[ldOff]);
            gld16(bS + (size_t)64 * DM,  &Bn[4096 + ldOff]);
            gld16(bS + (size_t)128 * DM, &Bn[2 * 4096 + ldOff]);
            gld16(aS,                    &An[ldOff]);
            gld16(aS + (size_t)64 * DM,  &An[4096 + ldOff]);
            gld16(aS + (size_t)128 * DM, &An[2 * 4096 + ldOff]);
            gld16(aS + (size_t)192 * DM, &An[3 * 4096 + ldOff]);
        }

        __builtin_amdgcn_s_setprio(1);
#pragma unroll
        for (int u = 0; u < 4; ++u)
#pragma unroll
            for (int v = 0; v < 6; ++v)
                acc[u][v] = __builtin_amdgcn_mfma_f32_16x16x32_bf16(
                    af0[u], bf0[v], acc[u][v], 0, 0, 0);
        __builtin_amdgcn_s_setprio(0);

        // ---- kk = 1 fragment reads ----
        bf16x8 af1[4], bf1[6];
#pragma unroll
        for (int u = 0; u < 4; ++u)
            af1[u] = *(const bf16x8*)&Ac[(wr * 64 + u * 16 + m16) * BK + (((4 | g) ^ sw) * 8)];
#pragma unroll
        for (int v = 0; v < 6; ++v)
            bf1[v] = *(const bf16x8*)&Bc[(wc * 96 + v * 16 + m16) * BK + (((4 | g) ^ sw) * 8)];

        __builtin_amdgcn_s_setprio(1);
#pragma unroll
        for (int u = 0; u < 4; ++u)
#pragma unroll
            for (int v = 0; v < 6; ++v)
                acc[u][v] = __builtin_amdgcn_mfma_f32_16x16x32_bf16(
                    af1[u], bf1[v], acc[u][v], 0, 0, 0);
        __builtin_amdgcn_s_setprio(0);

        if (hn)
            asm volatile("s_waitcnt vmcnt(0)" ::: "memory");
        __builtin_amdgcn_s_barrier();
        __builtin_amdgcn_sched_barrier(0);
    }

    // epilogue — same math as proven kernel; sec per fragment (wave-uniform).
    const int q4 = g * 4;
#pragma unroll
    for (int v = 0; v < 6; ++v) {
        const int col = colBase + wc * 96 + v * 16 + m16;
        const int sec = col >> 10;
        const int h   = (col >> 6) & (NHEAD - 1);
        const int dh  = col & 63;
        if (sec < 2) {
            const float bi = (sec == 0 ? b0 : b1)[col & (DM - 1)];
            const float sc = (sec == 0) ? 0.125f * __expf(-beta[h]) : 1.0f;
            unsigned short* base = Cb + (size_t)sec * MROWS * DM;
#pragma unroll
            for (int u = 0; u < 4; ++u)
#pragma unroll
                for (int r = 0; r < 4; ++r) {
                    const int row = rowBase + wr * 64 + u * 16 + q4 + r;
                    const int s = row >> 1, bb = row & 1;
                    const int z = bb * NHEAD + h;
                    base[((size_t)z * S_LEN + s) * DHEAD + dh] =
                        f2b((acc[u][v][r] + bi) * sc);
                }
        } else {
            unsigned short* vtb = Cb + (size_t)2 * MROWS * DM;
            const float bi = b2[col & (DM - 1)];
#pragma unroll
            for (int u = 0; u < 4; ++u) {
                const int row0 = rowBase + wr * 64 + u * 16 + q4;
                const int s0   = row0 >> 1;
                ushort2 p0, p1;
                p0.x = f2b(acc[u][v][0] + bi);   // bb=0, s0
                p0.y = f2b(acc[u][v][2] + bi);   // bb=0, s0+1
                p1.x = f2b(acc[u][v][1] + bi);   // bb=1, s0
                p1.y = f2b(acc[u][v][3] + bi);   // bb=1, s0+1
                *(ushort2*)(vtb + ((size_t)(h * DHEAD + dh) * S_LEN + s0)) = p0;
                *(ushort2*)(vtb + ((size_t)((NHEAD + h) * DHEAD + dh) * S_LEN + s0)) = p1;
            }
        }
    }
}

// ---------------------------------------------------------------------------
// R14 gemm_out: 128x64 tile, BK=64, 4 waves as 2x2 (wave 64x32).
// Grid 16x32 = 512 blocks = 2 blocks/CU (fixes R13's 1-block/CU, 1-wave/SIMD
// stall: no TLP to hide the per-tile drain). LDS 48 KB dbuf. Same one-barrier
// counted schedule as gemm_qkv.
// ---------------------------------------------------------------------------
__global__ __launch_bounds__(256, 2)
void gemm_out(const unsigned short* __restrict__ A,
              const unsigned short* __restrict__ BT,
              const float* __restrict__ bias,
              float* __restrict__ Cf)
{
    __shared__ unsigned short As[2][OM * BK];   // 2 x 16 KB
    __shared__ unsigned short Bs[2][ON * BK];   // 2 x 8 KB

    const int t  = threadIdx.x;
    const int wv = t >> 6, ln = t & 63;
    const int wr = wv >> 1, wc = wv & 1;        // 2x2, wave 64x32
    const int m16 = ln & 15, g = ln >> 4;
    const int sw  = m16 & 7;

    const int rowBase = blockIdx.y * OM;
    const int colBase = blockIdx.x * ON;

    // staging (256 threads): slot j covers rows 32j..32j+31 ((row&7) const)
    const int sr  = t >> 3;                   // 0..31
    const int scx = (t & 7) ^ (sr & 7);
    const size_t gOff = (size_t)sr * DM + scx * 8;
    const int    ldOff = t * 8;

    f32x4 acc[4][2];
#pragma unroll
    for (int u = 0; u < 4; ++u)
#pragma unroll
        for (int v = 0; v < 2; ++v)
            acc[u][v] = (f32x4){0.f, 0.f, 0.f, 0.f};

    // prologue: stage K-tile 0
    {
        const unsigned short* a0 = A  + (size_t)rowBase * DM + gOff;
        const unsigned short* bt = BT + (size_t)colBase * DM + gOff;
#pragma unroll
        for (int j = 0; j < 4; ++j)
            gld16(a0 + (size_t)(j * 32) * DM, &As[0][j * 2048 + ldOff]);
#pragma unroll
        for (int j = 0; j < 2; ++j)
            gld16(bt + (size_t)(j * 32) * DM, &Bs[0][j * 2048 + ldOff]);
        asm volatile("s_waitcnt vmcnt(0)" ::: "memory");
        __builtin_amdgcn_s_barrier();
        __builtin_amdgcn_sched_barrier(0);
    }

    for (int kt = 0; kt < DM / BK; ++kt) {
        const int cur = kt & 1;
        const unsigned short* Ac = As[cur];
        const unsigned short* Bc = Bs[cur];
        unsigned short* An = As[cur ^ 1];
        unsigned short* Bn = Bs[cur ^ 1];
        const bool hn = (kt < DM / BK - 1);
        const unsigned short* aS = A  + (size_t)rowBase * DM + (kt + 1) * BK + gOff;
        const unsigned short* bS = BT + (size_t)colBase * DM + (kt + 1) * BK + gOff;

        bf16x8 af0[4], bf0[2];
#pragma unroll
        for (int u = 0; u < 4; ++u)
            af0[u] = *(const bf16x8*)&Ac[(wr * 64 + u * 16 + m16) * BK + ((g ^ sw) * 8)];
#pragma unroll
        for (int v = 0; v < 2; ++v)
            bf0[v] = *(const bf16x8*)&Bc[(wc * 32 + v * 16 + m16) * BK + ((g ^ sw) * 8)];

        if (hn) {
#pragma unroll
            for (int j = 0; j < 4; ++j)
                gld16(aS + (size_t)(j * 32) * DM, &An[j * 2048 + ldOff]);
#pragma unroll
            for (int j = 0; j < 2; ++j)
                gld16(bS + (size_t)(j * 32) * DM, &Bn[j * 2048 + ldOff]);
        }

        __builtin_amdgcn_s_setprio(1);
#pragma unroll
        for (int u = 0; u < 4; ++u)
#pragma unroll
            for (int v = 0; v < 2; ++v)
                acc[u][v] = __builtin_amdgcn_mfma_f32_16x16x32_bf16(
                    af0[u], bf0[v], acc[u][v], 0, 0, 0);
        __builtin_amdgcn_s_setprio(0);

        bf16x8 af1[4], bf1[2];
#pragma unroll
        for (int u = 0; u < 4; ++u)
            af1[u] = *(const bf16x8*)&Ac[(wr * 64 + u * 16 + m16) * BK + (((4 | g) ^ sw) * 8)];
#pragma unroll
        for (int v = 0; v < 2; ++v)
            bf1[v] = *(const bf16x8*)&Bc[(wc * 32 + v * 16 + m16) * BK + (((4 | g) ^ sw) * 8)];

        __builtin_amdgcn_s_setprio(1);
#pragma unroll
        for (int u = 0; u < 4; ++u)
#pragma unroll
            for (int v = 0; v < 2; ++v)
                acc[u][v] = __builtin_amdgcn_mfma_f32_16x16x32_bf16(
                    af1[u], bf1[v], acc[u][v], 0, 0, 0);
        __builtin_amdgcn_s_setprio(0);

        if (hn)
            asm volatile("s_waitcnt vmcnt(0)" ::: "memory");
        __builtin_amdgcn_s_barrier();
        __builtin_amdgcn_sched_barrier(0);
    }

    const int q4 = g * 4;
#pragma unroll
    for (int v = 0; v < 2; ++v) {
        const int col = colBase + wc * 32 + v * 16 + m16;
        const float bi = bias[col];
#pragma unroll
        for (int u = 0; u < 4; ++u)
#pragma unroll
            for (int r = 0; r < 4; ++r) {
                const int row = rowBase + wr * 64 + u * 16 + q4 + r;
                Cf[(size_t)row * DM + col] = acc[u][v][r] + bi;
            }
    }
}

// ---------------------------------------------------------------------------
// R14 attn: same math as R11 (no online max; sink l0=1; exp(-1e30)==0) but
// async K/V staging via global_load_lds into double-buffered LDS with XOR
// chunk pre-swizzle on the GLOBAL source + XOR on the read address (replaces
// the KP=72 pad; conflict-free reads). ONE s_barrier per tile (was 3
// __syncthreads): staging for tile c+1 issued at top of tile c, vmcnt(0)
// just before the end barrier. P round-trip is WAVE-PRIVATE (write rows
// wv*16+g*4+r, read rows wv*16+m16) -> lgkmcnt(0) only, no barrier.
// LDS: 2x8KB K + 2x8KB V + 17.4KB Ps = 49.8 KB -> 3 blocks/CU.
// ---------------------------------------------------------------------------
__global__ __launch_bounds__(256, 3)
void attn_mfma(const unsigned short* __restrict__ q,
               const unsigned short* __restrict__ k,
               const unsigned short* __restrict__ vt,
               unsigned short* __restrict__ ao)
{
    __shared__ unsigned short Ks[2][64 * 64];   // [key][d-chunk swz]
    __shared__ unsigned short Vs[2][64 * 64];   // [dh][key-chunk swz]
    __shared__ float Ps[64][PPAD];              // [wave*16 + qrow][key]

    const int t   = threadIdx.x;
    const int wv  = t >> 6, ln = t & 63;
    const int m16 = ln & 15, g = ln >> 4;
    const int sw  = m16 & 7;
    const int z   = blockIdx.y;
    const int q0  = blockIdx.x * 64;
    const size_t zbase = (size_t)z * S_LEN * DHEAD;

    // staging geometry: slot j = t + 256*j covers row sr+32j, chunk t&7;
    // source chunk pre-swizzled by row&7 (constant across slots: 32%8==0).
    const int sr  = t >> 3;                   // 0..31
    const int scx = (t & 7) ^ (sr & 7);
    const unsigned short* kS = k  + zbase + (size_t)sr * DHEAD + scx * 8;
    const unsigned short* vS = vt + ((size_t)z * DHEAD + sr) * S_LEN + scx * 8;
    const int ldOff = t * 8;                  // shorts

    const unsigned short* qrow = q + zbase + (size_t)(q0 + wv * 16 + m16) * DHEAD;
    bf16x8 qf0 = *(const bf16x8*)(qrow + g * 8);
    bf16x8 qf1 = *(const bf16x8*)(qrow + 32 + g * 8);

    f32x4 oacc[4];
#pragma unroll
    for (int v4 = 0; v4 < 4; ++v4) oacc[v4] = (f32x4){0.f, 0.f, 0.f, 0.f};
    float lr[4];
#pragma unroll
    for (int r = 0; r < 4; ++r) lr[r] = 1.f;   // sink: exp(0)

    const int c0 = (blockIdx.x < 4) ? (4 - (int)blockIdx.x) : 0;

    // prologue: stage tile c0 into buffer 0
    {
        const int kb = q0 - 256 + c0 * 64;
        gld16(kS + (size_t)kb * DHEAD,        &Ks[0][ldOff]);
        gld16(kS + (size_t)(kb + 32) * DHEAD, &Ks[0][2048 + ldOff]);
        gld16(vS + kb,                        &Vs[0][ldOff]);
        gld16(vS + (size_t)32 * S_LEN + kb,   &Vs[0][2048 + ldOff]);
        asm volatile("s_waitcnt vmcnt(0)" ::: "memory");
        __builtin_amdgcn_s_barrier();
        __builtin_amdgcn_sched_barrier(0);
    }

    for (int c = c0; c < 5; ++c) {
        const int cur = (c - c0) & 1;
        const int kb  = q0 - 256 + c * 64;
        const bool hn = (c < 4);

        // stage next tile into buf cur^1 (waited at end of this iter)
        if (hn) {
            const int kn = kb + 64;
            gld16(kS + (size_t)kn * DHEAD,        &Ks[cur ^ 1][ldOff]);
            gld16(kS + (size_t)(kn + 32) * DHEAD, &Ks[cur ^ 1][2048 + ldOff]);
            gld16(vS + kn,                        &Vs[cur ^ 1][ldOff]);
            gld16(vS + (size_t)32 * S_LEN + kn,   &Vs[cur ^ 1][2048 + ldOff]);
        }

        // S = Q K^T
        f32x4 sacc[4];
#pragma unroll
        for (int v4 = 0; v4 < 4; ++v4) {
            sacc[v4] = (f32x4){0.f, 0.f, 0.f, 0.f};
            bf16x8 kf0 = *(const bf16x8*)&Ks[cur][(v4 * 16 + m16) * 64 + ((g ^ sw) * 8)];
            sacc[v4] = __builtin_amdgcn_mfma_f32_16x16x32_bf16(qf0, kf0, sacc[v4], 0, 0, 0);
            bf16x8 kf1 = *(const bf16x8*)&Ks[cur][(v4 * 16 + m16) * 64 + (((4 | g) ^ sw) * 8)];
            sacc[v4] = __builtin_amdgcn_mfma_f32_16x16x32_bf16(qf1, kf1, sacc[v4], 0, 0, 0);
        }

        // mask + exp + row-sum (no max): P -> LDS (wave-private rows)
        const bool mhi = (c == 4), mlo = (c == 0);
#pragma unroll
        for (int r = 0; r < 4; ++r) {
            const int ig = q0 + wv * 16 + g * 4 + r;
            float rsum = 0.f;
#pragma unroll
            for (int v4 = 0; v4 < 4; ++v4) {
                const int jg = kb + v4 * 16 + m16;
                float x = sacc[v4][r];
                const bool valid = (!mhi || jg <= ig) && (!mlo || jg >= ig - (WIN - 1));
                x = valid ? x : -1e30f;
                const float pp = __expf(x);     // masked -> exactly 0
                Ps[wv * 16 + g * 4 + r][v4 * 16 + m16] = pp;
                rsum += pp;
            }
#pragma unroll
            for (int off = 1; off < 16; off <<= 1)
                rsum += __shfl_xor(rsum, off, 64);
            lr[r] += rsum;
        }

        // wave-private round-trip: LDS drain only, no block barrier
        asm volatile("s_waitcnt lgkmcnt(0)" ::: "memory");
        __builtin_amdgcn_sched_barrier(0);

        // O += P V
        const float* prow = &Ps[wv * 16 + m16][0];
        bf16x8 pf0 = pack8(*(const float4*)(prow + g * 8),
                           *(const float4*)(prow + g * 8 + 4));
        bf16x8 pf1 = pack8(*(const float4*)(prow + 32 + g * 8),
                           *(const float4*)(prow + 32 + g * 8 + 4));
#pragma unroll
        for (int v4 = 0; v4 < 4; ++v4) {
            bf16x8 vf0 = *(const bf16x8*)&Vs[cur][(v4 * 16 + m16) * 64 + ((g ^ sw) * 8)];
            oacc[v4] = __builtin_amdgcn_mfma_f32_16x16x32_bf16(pf0, vf0, oacc[v4], 0, 0, 0);
            bf16x8 vf1 = *(const bf16x8*)&Vs[cur][(v4 * 16 + m16) * 64 + (((4 | g) ^ sw) * 8)];
            oacc[v4] = __builtin_amdgcn_mfma_f32_16x16x32_bf16(pf1, vf1, oacc[v4], 0, 0, 0);
        }

        if (hn) {
            asm volatile("s_waitcnt vmcnt(0)" ::: "memory");
            __builtin_amdgcn_s_barrier();
            __builtin_amdgcn_sched_barrier(0);
        }
    }

    const int bb = z >> 4, h = z & 15;
#pragma unroll
    for (int r = 0; r < 4; ++r) {
        const int ig  = q0 + wv * 16 + g * 4 + r;
        const float inv = 1.f / lr[r];
#pragma unroll
        for (int v4 = 0; v4 < 4; ++v4)
            ao[(size_t)(ig * BATCH + bb) * DM + h * DHEAD + v4 * 16 + m16] =
                f2b(oacc[v4][r] * inv);
    }
}

// ---------------------------------------------------------------------------
extern "C" void kernel_launch(void* const* d_in, const int* in_sizes, int n_in,
                              void* d_out, int out_size, void* d_ws, size_t ws_size,
                              hipStream_t stream)
{
    const float* x    = (const float*)d_in[0];
    const float* beta = (const float*)d_in[1];
    const float* Wq   = (const float*)d_in[2];
    const float* bq   = (const float*)d_in[3];
    const float* Wk   = (const float*)d_in[4];
    const float* bk   = (const float*)d_in[5];
    const float* Wv   = (const float*)d_in[6];
    const float* bv   = (const float*)d_in[7];
    const float* Wo   = (const float*)d_in[8];
    const float* bo   = (const float*)d_in[9];
    float* out = (float*)d_out;

    unsigned short* w = (unsigned short*)d_ws;
    const size_t seg = (size_t)MROWS * DM;      // 4M elems
    unsigned short* qb  = w;                    // q (z,s,dh)
    unsigned short* kb  = w + seg;              // k (z,s,dh)
    unsigned short* vtb = w + 2 * seg;          // v^T (z,dh,s) -- direct from QKV
    unsigned short* ab  = w + 3 * seg;          // attn out, row-major
    unsigned short* xb  = w + 4 * seg;          // x bf16
    unsigned short* wtq = w + 5 * seg;          // WqT|WkT|WvT|WoT contiguous
    unsigned short* wtk = wtq + (size_t)DM * DM;
    unsigned short* wtv = wtk + (size_t)DM * DM;
    unsigned short* wto = wtv + (size_t)DM * DM;

    cvtx<<<4096, 256, 0, stream>>>(x, xb);
    twcvt4<<<dim3(32, 32, 4), 256, 0, stream>>>(Wq, Wk, Wv, Wo, wtq, wtk, wtv, wto);

    // fused Q+K+V projection: 256x192 tiles -> 16x16 = 256 blocks (1/CU)
    gemm_qkv<<<dim3(3072 / BN, MROWS / BM), 512, 0, stream>>>(
        xb, wtq, bq, bk, bv, beta, qb);

    attn_mfma<<<dim3(S_LEN / 64, BATCH * NHEAD), 256, 0, stream>>>(qb, kb, vtb, ab);

    // output projection: 128x64 tiles -> 16x32 = 512 blocks (2/CU)
    gemm_out<<<dim3(DM / ON, MROWS / OM), 256, 0, stream>>>(ab, wto, bo, out);
}